// Round 9
// baseline (150.772 us; speedup 1.0000x reference)
//
#include <hip/hip_runtime.h>

// StableZeroDiv: out = x * (y != 0 ? 1/y : 0), elementwise fp32.
// 67,108,864 fp32 elems/tensor; 768 MB logical traffic -> HBM-bound.
// R8: extend R7's winning lever (block-contiguous windows + straight-line
// multi-load body). UNROLL 4->8: 32 KB contiguous window per buffer per
// block, 16 back-to-back load issues per thread (R7's VGPR=20 showed the
// allocator only kept ~3-4 of the intended 8 in flight). Flat launch,
// plain stores, rcp select (absmax 0.25 vs 4.98e5 threshold).

#define UNROLL 8

__global__ void __launch_bounds__(256)
StableZeroDiv_16561393894029_kernel(const float4* __restrict__ x4,
                                    const float4* __restrict__ y4,
                                    float4* __restrict__ o4) {
    // Each block: contiguous chunk of UNROLL*256 float4 (32 KB / buffer).
    const int base = blockIdx.x * (UNROLL * 256) + threadIdx.x;
    float4 xv[UNROLL], yv[UNROLL];
    // Issue all loads before any use -> up to 16 outstanding vmem ops.
#pragma unroll
    for (int k = 0; k < UNROLL; ++k) {
        xv[k] = x4[base + k * 256];
        yv[k] = y4[base + k * 256];
    }
#pragma unroll
    for (int k = 0; k < UNROLL; ++k) {
        float4 ov;
        ov.x = (yv[k].x != 0.0f) ? xv[k].x * __builtin_amdgcn_rcpf(yv[k].x) : 0.0f;
        ov.y = (yv[k].y != 0.0f) ? xv[k].y * __builtin_amdgcn_rcpf(yv[k].y) : 0.0f;
        ov.z = (yv[k].z != 0.0f) ? xv[k].z * __builtin_amdgcn_rcpf(yv[k].z) : 0.0f;
        ov.w = (yv[k].w != 0.0f) ? xv[k].w * __builtin_amdgcn_rcpf(yv[k].w) : 0.0f;
        o4[base + k * 256] = ov;
    }
}

// Grid-stride float4 kernel for any remainder [start4, n4).
__global__ void __launch_bounds__(256)
StableZeroDiv_16561393894029_rem(const float4* __restrict__ x4,
                                 const float4* __restrict__ y4,
                                 float4* __restrict__ o4,
                                 int start4, int n4) {
    const int stride = gridDim.x * blockDim.x;
    for (int i = start4 + blockIdx.x * blockDim.x + threadIdx.x; i < n4;
         i += stride) {
        float4 xv = x4[i];
        float4 yv = y4[i];
        float4 ov;
        ov.x = (yv.x != 0.0f) ? xv.x * __builtin_amdgcn_rcpf(yv.x) : 0.0f;
        ov.y = (yv.y != 0.0f) ? xv.y * __builtin_amdgcn_rcpf(yv.y) : 0.0f;
        ov.z = (yv.z != 0.0f) ? xv.z * __builtin_amdgcn_rcpf(yv.z) : 0.0f;
        ov.w = (yv.w != 0.0f) ? xv.w * __builtin_amdgcn_rcpf(yv.w) : 0.0f;
        o4[i] = ov;
    }
}

// Scalar tail for n % 4 != 0 (not hit at the bench shape).
__global__ void __launch_bounds__(64)
StableZeroDiv_16561393894029_tail(const float* __restrict__ x,
                                  const float* __restrict__ y,
                                  float* __restrict__ o,
                                  int start, int n) {
    int i = start + blockIdx.x * blockDim.x + threadIdx.x;
    if (i < n) {
        float yv = y[i];
        o[i] = (yv != 0.0f) ? x[i] * __builtin_amdgcn_rcpf(yv) : 0.0f;
    }
}

extern "C" void kernel_launch(void* const* d_in, const int* in_sizes, int n_in,
                              void* d_out, int out_size, void* d_ws, size_t ws_size,
                              hipStream_t stream) {
    const float* x = (const float*)d_in[0];
    const float* y = (const float*)d_in[1];
    float* out = (float*)d_out;
    const int n = in_sizes[0];          // 67,108,864
    const int n4 = n / 4;               // 16,777,216 float4 elements

    const int chunk = UNROLL * 256;     // float4 per block (2048)
    const int nblocks = n4 / chunk;     // 8192 exactly at bench shape
    const int covered = nblocks * chunk;

    if (nblocks > 0) {
        StableZeroDiv_16561393894029_kernel<<<nblocks, 256, 0, stream>>>(
            (const float4*)x, (const float4*)y, (float4*)out);
    }
    if (n4 > covered) {
        StableZeroDiv_16561393894029_rem<<<64, 256, 0, stream>>>(
            (const float4*)x, (const float4*)y, (float4*)out, covered, n4);
    }
    const int tail_start = n4 * 4;
    if (n > tail_start) {
        StableZeroDiv_16561393894029_tail<<<1, 64, 0, stream>>>(
            x, y, out, tail_start, n);
    }
}

// Round 10
// 144.810 us; speedup vs baseline: 1.0412x; 1.0412x over previous
//
#include <hip/hip_runtime.h>

// StableZeroDiv: out = x * (y != 0 ? 1/y : 0), elementwise fp32.
// 67,108,864 fp32 elems/tensor; 768 MB logical traffic -> HBM/stream-bound.
// R9: exact revert to R7 (best: 145.6 us = 5.27 TB/s logical, 84% of the
// 6.29 TB/s copy ceiling). R8's UNROLL=8 traded occupancy (80->48%) for
// ILP at a net loss; NT stores proven null on FETCH_SIZE (R5/R6).
// Structure: flat launch, each block owns a contiguous 16 KB window per
// buffer, each thread 4 float4s at +k*256 (8 loads in flight, VGPR=20,
// 8 waves/SIMD). rcp select: absmax 0.25 vs 4.98e5 threshold.

#define UNROLL 4

__global__ void __launch_bounds__(256)
StableZeroDiv_16561393894029_kernel(const float4* __restrict__ x4,
                                    const float4* __restrict__ y4,
                                    float4* __restrict__ o4) {
    // Each block: contiguous chunk of UNROLL*256 float4 (16 KB / buffer).
    const int base = blockIdx.x * (UNROLL * 256) + threadIdx.x;
    float4 xv[UNROLL], yv[UNROLL];
    // 8 independent loads in flight before any vmcnt wait.
#pragma unroll
    for (int k = 0; k < UNROLL; ++k) {
        xv[k] = x4[base + k * 256];
        yv[k] = y4[base + k * 256];
    }
#pragma unroll
    for (int k = 0; k < UNROLL; ++k) {
        float4 ov;
        ov.x = (yv[k].x != 0.0f) ? xv[k].x * __builtin_amdgcn_rcpf(yv[k].x) : 0.0f;
        ov.y = (yv[k].y != 0.0f) ? xv[k].y * __builtin_amdgcn_rcpf(yv[k].y) : 0.0f;
        ov.z = (yv[k].z != 0.0f) ? xv[k].z * __builtin_amdgcn_rcpf(yv[k].z) : 0.0f;
        ov.w = (yv[k].w != 0.0f) ? xv[k].w * __builtin_amdgcn_rcpf(yv[k].w) : 0.0f;
        o4[base + k * 256] = ov;
    }
}

// Grid-stride float4 kernel for any remainder [start4, n4).
__global__ void __launch_bounds__(256)
StableZeroDiv_16561393894029_rem(const float4* __restrict__ x4,
                                 const float4* __restrict__ y4,
                                 float4* __restrict__ o4,
                                 int start4, int n4) {
    const int stride = gridDim.x * blockDim.x;
    for (int i = start4 + blockIdx.x * blockDim.x + threadIdx.x; i < n4;
         i += stride) {
        float4 xv = x4[i];
        float4 yv = y4[i];
        float4 ov;
        ov.x = (yv.x != 0.0f) ? xv.x * __builtin_amdgcn_rcpf(yv.x) : 0.0f;
        ov.y = (yv.y != 0.0f) ? xv.y * __builtin_amdgcn_rcpf(yv.y) : 0.0f;
        ov.z = (yv.z != 0.0f) ? xv.z * __builtin_amdgcn_rcpf(yv.z) : 0.0f;
        ov.w = (yv.w != 0.0f) ? xv.w * __builtin_amdgcn_rcpf(yv.w) : 0.0f;
        o4[i] = ov;
    }
}

// Scalar tail for n % 4 != 0 (not hit at the bench shape).
__global__ void __launch_bounds__(64)
StableZeroDiv_16561393894029_tail(const float* __restrict__ x,
                                  const float* __restrict__ y,
                                  float* __restrict__ o,
                                  int start, int n) {
    int i = start + blockIdx.x * blockDim.x + threadIdx.x;
    if (i < n) {
        float yv = y[i];
        o[i] = (yv != 0.0f) ? x[i] * __builtin_amdgcn_rcpf(yv) : 0.0f;
    }
}

extern "C" void kernel_launch(void* const* d_in, const int* in_sizes, int n_in,
                              void* d_out, int out_size, void* d_ws, size_t ws_size,
                              hipStream_t stream) {
    const float* x = (const float*)d_in[0];
    const float* y = (const float*)d_in[1];
    float* out = (float*)d_out;
    const int n = in_sizes[0];          // 67,108,864
    const int n4 = n / 4;               // 16,777,216 float4 elements

    const int chunk = UNROLL * 256;     // float4 per block (1024)
    const int nblocks = n4 / chunk;     // 16384 exactly at bench shape
    const int covered = nblocks * chunk;

    if (nblocks > 0) {
        StableZeroDiv_16561393894029_kernel<<<nblocks, 256, 0, stream>>>(
            (const float4*)x, (const float4*)y, (float4*)out);
    }
    if (n4 > covered) {
        StableZeroDiv_16561393894029_rem<<<64, 256, 0, stream>>>(
            (const float4*)x, (const float4*)y, (float4*)out, covered, n4);
    }
    const int tail_start = n4 * 4;
    if (n > tail_start) {
        StableZeroDiv_16561393894029_tail<<<1, 64, 0, stream>>>(
            x, y, out, tail_start, n);
    }
}